// Round 8
// baseline (243.289 us; speedup 1.0000x reference)
//
#include <hip/hip_runtime.h>

#define H 64
#define NEDGE 50000
#define NNODE 12000
#define EPAD 50176

typedef _Float16 f16;
typedef _Float16 h8 __attribute__((ext_vector_type(8)));
typedef float f4 __attribute__((ext_vector_type(4)));
typedef float fv16 __attribute__((ext_vector_type(16)));

// workspace layout (bytes)
#define O_EDGEH 0ull            // edge f16 padded [50176][64]        = 6,422,528
#define O_W2G   6422528ull      // swizzled W2 f16 (64 chunks x 16KB) = 1,048,576
#define O_B2G   7471104ull      // swizzled b2 f16 (K=64 chunk, 8KB)  — MUST follow w2g (tail reads w2g+64*16384)
#define O_W1G   7479296ull      // swizzled W1 f16 (16KB)
#define O_WG    7495680ull      // GRU combined weights f16 (64KB)
#define O_AGG   7561216ull      // agg f32 [12000][64]                = 3,072,000

__device__ __forceinline__ fv16 zero16() {
  fv16 z;
#pragma unroll
  for (int i = 0; i < 16; ++i) z[i] = 0.f;
  return z;
}

// ---------------- prep: agg zero, edge->f16, W2/b2/W1/Wgru -> 32x32x16 MFMA-B granule order
// w2g: chunk h in [0,64); granule g=(s*2+nh)*64+l, elem i: W2[(h*64 + nh*32+(l&31))*128 + s*16+((l>>5)<<3)+i]
// b2g: granule g=(s*2+nh)*64+l (s<4), elem i: b2[(s*16+((l>>5)<<3)+i)*64 + nh*32+(l&31)]
// w1g: granule g=(s*4+nt)*64+l (s<4,nt<4), elem i: W1[(nt*32+(l&31))*64 + s*16+((l>>5)<<3)+i]
__global__ __launch_bounds__(256) void k_prep(const float* __restrict__ edge, const float* __restrict__ W1,
                                              const float* __restrict__ W2, const float* __restrict__ b2,
                                              const float* __restrict__ Wih, const float* __restrict__ Whh,
                                              f16* __restrict__ edgeh, f16* __restrict__ w1g, f16* __restrict__ w2g,
                                              f16* __restrict__ b2g, f16* __restrict__ wg, float* __restrict__ agg) {
  int bid = blockIdx.x;
  int t = threadIdx.x;
  if (bid < 750) {  // agg zero
    int id = bid * 256 + t;
    *(f4*)(agg + (long)id * 4) = (f4){0.f, 0.f, 0.f, 0.f};
    return;
  }
  if (bid < 2318) {  // edgeh cast, 8 elems/thread (EPAD rows, pad zeroed)
    long id8 = (long)(bid - 750) * 256 + t;
    long e = id8 >> 3;
    int c = (int)(id8 & 7) * 8;
    h8 o = {};
    if (e < NEDGE) {
      const float* p = edge + e * 64 + c;
      f4 v0 = *(const f4*)p, v1 = *(const f4*)(p + 4);
#pragma unroll
      for (int j = 0; j < 4; ++j) { o[j] = (f16)v0[j]; o[4 + j] = (f16)v1[j]; }
    }
    *(h8*)(edgeh + e * 64 + c) = o;
    return;
  }
  if (bid < 4366) {  // w2g: 524288 f16
    int id = (bid - 2318) * 256 + t;
    int i = id & 7, l = (id >> 3) & 63, nh = (id >> 9) & 1, s = (id >> 10) & 7, h = id >> 13;
    int n = nh * 32 + (l & 31), j = s * 16 + ((l >> 5) << 3) + i;
    w2g[id] = (f16)W2[(h * 64 + n) * 128 + j];
    return;
  }
  if (bid < 4382) {  // b2g: 4096 f16
    int id = (bid - 4366) * 256 + t;
    int i = id & 7, l = (id >> 3) & 63, nh = (id >> 9) & 1, s = id >> 10;
    int n = nh * 32 + (l & 31), k = s * 16 + ((l >> 5) << 3) + i;
    b2g[id] = (f16)b2[k * 64 + n];
    return;
  }
  if (bid < 4414) {  // w1g: 8192 f16
    int id = (bid - 4382) * 256 + t;
    int i = id & 7, l = (id >> 3) & 63, nt = (id >> 9) & 3, s = id >> 11;
    int n = nt * 32 + (l & 31), k = s * 16 + ((l >> 5) << 3) + i;
    w1g[id] = (f16)W1[n * 64 + k];
    return;
  }
  // wg: GRU combined B matrix [128k][256n] in 16x16x32 granule order, 32768 f16
  {
    int id = (bid - 4414) * 256 + t;
    int ii = id & 7, l = (id >> 3) & 63, tt = (id >> 9) & 15, s = id >> 13;
    int k = s * 32 + ((l >> 4) << 3) + ii, n = tt * 16 + (l & 15);
    float v;
    if (n < 128) v = (k < 64) ? Wih[n * 64 + k] : Whh[n * 64 + (k - 64)];
    else if (n < 192) v = (k < 64) ? Wih[n * 64 + k] : 0.f;
    else v = (k < 64) ? 0.f : Whh[(n - 64) * 64 + (k - 64)];
    wg[id] = (f16)v;
  }
}

// ---------------- fused msg kernel v8: 64 edges/block, NO hs-split (each block owns all 64 h + b2 tail).
// Grid 782 ~= every block resident (3/CU). Waves = j-QUARTER kq=wave: per wave M=64 (2 mt), N=64 (2 nh),
// K=32/h (2 s-granules). Diagnosis r0/r3/v7: three different structures all converge at MfmaUtil~30%,
// VALUBusy~0.9x -- per-wave ILP starvation: v7's step = 8 MFMA (256 SIMD-cyc at 32cyc/MFMA) on only 2
// acc chains, each MFMA gated on a just-computed VALU a=eh*v (1:1 VALU coupling at N=32).
// v8: N=64 doubles MFMA per A-scale (VALU:MFMA 1:8) and gives 4 independent acc chains; per-step MFMA
// (256 cyc) x 3 waves >> L2 latency so depth-1 register dbuf covers. No LDS/barriers in h-loop.
// Dropping hs-split halves prologue work, FETCH, and atomic traffic (scatter once per edge-tile).
// Regs: ehreg 16 + B dbuf 32 + acc 64 + vh 8 + misc ~30 -> fits (256,3) (v7 analog measured 64+32).
// K-quarter reduction: 3 pairwise LDS passes over the dead 16KB eh_s region (static acc indexing).
__global__ __launch_bounds__(256, 3) void k_msg(const float* __restrict__ node,
                                                const int* __restrict__ src, const int* __restrict__ dst,
                                                const f16* __restrict__ edgeh, const f16* __restrict__ w1g,
                                                const f16* __restrict__ w2g, const float* __restrict__ b1,
                                                float* __restrict__ agg) {
  // [0,16384) eh_s (phases 1-2, 64 rows x 256B) / red (f32 exchange, 4 x 4KB)
  // [16384,25600) vT f16 [64 e][72] (pitch 144B)
  // [25600,25856) sdst (64 int) | [25856,26368) b1s (128 f32)
  __shared__ __align__(16) char lds[26368];
  f16* eh_s = (f16*)lds;
  f16* vT = (f16*)(lds + 16384);
  int* sdst = (int*)(lds + 25600);
  float* b1s = (float*)(lds + 25856);

  int t = threadIdx.x;
  int e_base = blockIdx.x * 64;

  // ---- phase 0: indices, b1, v gather -> vT (4 threads/row, 16 f32 each)
  if (t < 64) {
    int eg = e_base + t;
    sdst[t] = (eg < NEDGE) ? dst[eg] : 0;
  } else if (t < 192) {
    b1s[t - 64] = b1[t - 64];
  }
  {
    int m = t >> 2, q = t & 3;
    int eg = e_base + m;
    int si = (eg < NEDGE) ? src[eg] : 0;
    const f4* nr = (const f4*)(node + (long)si * 64 + q * 16);
    f4 v0 = nr[0], v1 = nr[1], v2 = nr[2], v3 = nr[3];
    h8 p0, p1;
#pragma unroll
    for (int j = 0; j < 4; ++j) {
      p0[j] = (f16)v0[j]; p0[4 + j] = (f16)v1[j];
      p1[j] = (f16)v2[j]; p1[4 + j] = (f16)v3[j];
    }
    *(h8*)(vT + m * 72 + q * 16) = p0;
    *(h8*)(vT + m * 72 + q * 16 + 8) = p1;
  }
  __syncthreads();

  int wave = t >> 6, lane = t & 63;
  int l31 = lane & 31, lh = lane >> 5;
  int kq = wave;                        // phase-3: j-quarter owner
  int nhk = wave & 1, mtk = wave >> 1;  // epilogue: kept N-half / kept M-half

  // ---- phase 1: eh = relu(edge @ W1^T + b1), M=64/N=128/K=64; wave covers N-block wave*32
  {
    h8 afr[2][4];
#pragma unroll
    for (int mt = 0; mt < 2; ++mt)
#pragma unroll
      for (int s = 0; s < 4; ++s)
        afr[mt][s] = *(const h8*)(edgeh + (long)(e_base + mt * 32 + l31) * 64 + s * 16 + lh * 8);
    h8 bfr[4];
#pragma unroll
    for (int s = 0; s < 4; ++s)
      bfr[s] = *(const h8*)(w1g + ((s * 4 + wave) * 64 + lane) * 8);
    fv16 acc_eh[2];
    acc_eh[0] = zero16(); acc_eh[1] = zero16();
#pragma unroll
    for (int s = 0; s < 4; ++s)
#pragma unroll
      for (int mt = 0; mt < 2; ++mt)
        acc_eh[mt] = __builtin_amdgcn_mfma_f32_32x32x16_f16(afr[mt][s], bfr[s], acc_eh[mt], 0, 0, 0);
    // write eh tile to LDS, swizzled granules, + b1 + relu
#pragma unroll
    for (int mt = 0; mt < 2; ++mt)
#pragma unroll
      for (int r = 0; r < 16; ++r) {
        int row = (r & 3) + 8 * (r >> 2) + 4 * lh;
        int e = mt * 32 + row;
        int n = wave * 32 + l31;
        float val = fmaxf(acc_eh[mt][r] + b1s[n], 0.f);
        int o = n >> 3;
        eh_s[e * 128 + ((o ^ (e & 15)) << 3) + (n & 7)] = (f16)val;
      }
  }
  __syncthreads();

  // ---- phase 2: eh fragments -> registers. Wave kq: all 64 rows x its K j-quarter (2 s-granules).
  h8 ehreg[2][2];
#pragma unroll
  for (int mt = 0; mt < 2; ++mt) {
    int e = mt * 32 + l31;
#pragma unroll
    for (int s = 0; s < 2; ++s) {
      int o = ((kq * 2 + s) * 2 + lh) ^ (e & 15);
      ehreg[mt][s] = *(const h8*)(eh_s + e * 128 + o * 8);
    }
  }
  __syncthreads();  // all eh_s reads retired before epilogue red writes

  // ---- phase 3: 64 h iterations, B from L2 into registers, double-buffered. NO barriers, NO LDS.
  fv16 acc[2][2];
  acc[0][0] = zero16(); acc[0][1] = zero16(); acc[1][0] = zero16(); acc[1][1] = zero16();
  const f16* vrow = vT + l31 * 72;  // row mt*32+l31 -> + mt*2304 f16

  // B granule bytes: h*16384 + (kq*4 + s*2 + nh)*1024 + lane*16
  const char* bb = (const char*)w2g + kq * 4096 + (long)lane * 16;

  h8 bA[4], bB[4];
#pragma unroll
  for (int q = 0; q < 4; ++q) bA[q] = *(const h8*)(bb + q * 1024);  // h=0

  auto step = [&](h8 (&bc)[4], h8 (&bn)[4], int h, f16 v0, f16 v1) {
    if (h < 63) {
      const char* bp = bb + (long)(h + 1) * 16384;
#pragma unroll
      for (int q = 0; q < 4; ++q) bn[q] = *(const h8*)(bp + q * 1024);
    }
#pragma unroll
    for (int s = 0; s < 2; ++s) {
      h8 a0 = ehreg[0][s] * v0;
      h8 a1 = ehreg[1][s] * v1;
      acc[0][0] = __builtin_amdgcn_mfma_f32_32x32x16_f16(a0, bc[s * 2 + 0], acc[0][0], 0, 0, 0);
      acc[0][1] = __builtin_amdgcn_mfma_f32_32x32x16_f16(a0, bc[s * 2 + 1], acc[0][1], 0, 0, 0);
      acc[1][0] = __builtin_amdgcn_mfma_f32_32x32x16_f16(a1, bc[s * 2 + 0], acc[1][0], 0, 0, 0);
      acc[1][1] = __builtin_amdgcn_mfma_f32_32x32x16_f16(a1, bc[s * 2 + 1], acc[1][1], 0, 0, 0);
    }
  };

#pragma unroll 1
  for (int hb = 0; hb < 8; ++hb) {
    h8 vh0 = *(const h8*)(vrow + hb * 8);
    h8 vh1 = *(const h8*)(vrow + 2304 + hb * 8);
#pragma unroll
    for (int hh = 0; hh < 8; ++hh) {
      int h = hb * 8 + hh;
      if (hh & 1) step(bB, bA, h, vh0[hh], vh1[hh]);
      else step(bA, bB, h, vh0[hh], vh1[hh]);
    }
  }

  // ---- b2 bias tail (K=64, wave's quarter = s-granule kq): A = v fragment directly
  {
    const char* btb = (const char*)w2g + (long)64 * 16384 + kq * 2048 + (long)lane * 16;
    h8 bt0 = *(const h8*)(btb);
    h8 bt1 = *(const h8*)(btb + 1024);
#pragma unroll
    for (int mt = 0; mt < 2; ++mt) {
      h8 a = *(const h8*)(vrow + mt * 2304 + (kq * 2 + lh) * 8);
      acc[mt][0] = __builtin_amdgcn_mfma_f32_32x32x16_f16(a, bt0, acc[mt][0], 0, 0, 0);
      acc[mt][1] = __builtin_amdgcn_mfma_f32_32x32x16_f16(a, bt1, acc[mt][1], 0, 0, 0);
    }
  }

  // ---- j-quarter reduction: 3 pairwise 16KB LDS passes over red (eh_s region, dead).
  // Pass 1/2: partner wave^1 (combine j within half) exchanging the non-kept N-half, per mt.
  // Pass 3: partner wave^2 (combine halves) exchanging the non-kept M-half of the kept N-half.
  // All acc indices static (rule #20).
  {
    float* red = (float*)lds;
    float* myp = red + wave * 1024;
    auto wrtile = [&](const fv16& a) {
#pragma unroll
      for (int r = 0; r < 4; ++r) {
        f4 q = {a[4 * r], a[4 * r + 1], a[4 * r + 2], a[4 * r + 3]};
        *(f4*)(myp + r * 256 + lane * 4) = q;
      }
    };
    auto addtile = [&](fv16& a, const float* p) {
#pragma unroll
      for (int r = 0; r < 4; ++r) {
        f4 q = *(const f4*)(p + r * 256 + lane * 4);
        a[4 * r] += q[0]; a[4 * r + 1] += q[1]; a[4 * r + 2] += q[2]; a[4 * r + 3] += q[3];
      }
    };
    const float* p1 = red + (wave ^ 1) * 1024;
    const float* p3 = red + (wave ^ 2) * 1024;
    // pass 1: mt=0, nh-exchange
    if (!nhk) wrtile(acc[0][1]); else wrtile(acc[0][0]);
    __syncthreads();
    if (!nhk) addtile(acc[0][0], p1); else addtile(acc[0][1], p1);
    __syncthreads();
    // pass 2: mt=1, nh-exchange
    if (!nhk) wrtile(acc[1][1]); else wrtile(acc[1][0]);
    __syncthreads();
    if (!nhk) addtile(acc[1][0], p1); else addtile(acc[1][1], p1);
    __syncthreads();
    // pass 3: mt-exchange of kept nh
    if (!mtk) { if (!nhk) wrtile(acc[1][0]); else wrtile(acc[1][1]); }
    else      { if (!nhk) wrtile(acc[0][0]); else wrtile(acc[0][1]); }
    __syncthreads();
    if (!mtk) { if (!nhk) addtile(acc[0][0], p3); else addtile(acc[0][1], p3); }
    else      { if (!nhk) addtile(acc[1][0], p3); else addtile(acc[1][1], p3); }
  }

  // ---- epilogue: atomic scatter of kept tile acc[mtk][nhk]: rows mtk*32+crow, cols nhk*32+l31
  {
    fv16 av;
    if (!mtk) { if (!nhk) av = acc[0][0]; else av = acc[0][1]; }
    else      { if (!nhk) av = acc[1][0]; else av = acc[1][1]; }
    int n = nhk * 32 + l31;
#pragma unroll
    for (int r = 0; r < 16; ++r) {
      int el = mtk * 32 + (r & 3) + 8 * (r >> 2) + 4 * lh;
      if (e_base + el < NEDGE) atomicAdd(&agg[(long)sdst[el] * 64 + n], av[r]);
    }
  }
}

// ---------------- GRU + LayerNorm via MFMA: 128 nodes/block, 4 waves M-split.
__global__ __launch_bounds__(256) void k_node(const float* __restrict__ agg, const float* __restrict__ hid,
                                              const f16* __restrict__ wg,
                                              const float* __restrict__ bih, const float* __restrict__ bhh,
                                              const float* __restrict__ gamma, const float* __restrict__ beta,
                                              float* __restrict__ out) {
  __shared__ __align__(16) f16 xh_s[128 * 136];
  __shared__ float bsum[128], bin_s[64], bhn_s[64], gam_s[64], bet_s[64];
  int t = threadIdx.x;
  int n0 = blockIdx.x * 128;

  if (t < 128) bsum[t] = bih[t] + bhh[t];
  else if (t < 192) bin_s[t - 128] = bih[t];
  else bhn_s[t - 192] = bhh[t - 64];
  if (t < 64) gam_s[t] = gamma[t];
  else if (t < 128) bet_s[t - 64] = beta[t - 64];

  {  // stage A = [relu(agg) | hid] as f16
    int m = t >> 1, half = t & 1;
    int mg = n0 + m;
    bool vld = mg < NNODE;
    const float* sp = half ? (hid + (long)mg * 64) : (agg + (long)mg * 64);
#pragma unroll
    for (int jj = 0; jj < 8; ++jj) {
      f4 v0 = {0, 0, 0, 0}, v1 = {0, 0, 0, 0};
      if (vld) { v0 = *(const f4*)(sp + jj * 8); v1 = *(const f4*)(sp + jj * 8 + 4); }
      h8 pk;
#pragma unroll
      for (int m2 = 0; m2 < 4; ++m2) {
        pk[m2] = (f16)(half ? v0[m2] : fmaxf(v0[m2], 0.f));
        pk[4 + m2] = (f16)(half ? v1[m2] : fmaxf(v1[m2], 0.f));
      }
      *(h8*)(xh_s + m * 136 + half * 64 + jj * 8) = pk;
    }
  }
  __syncthreads();

  int wave = t >> 6, lane = t & 63;
  int l15 = lane & 15, lq = lane >> 4;

  f4 acc[2][16];
#pragma unroll
  for (int g = 0; g < 2; ++g)
#pragma unroll
    for (int tt = 0; tt < 16; ++tt) acc[g][tt] = (f4){0.f, 0.f, 0.f, 0.f};

#pragma unroll
  for (int s = 0; s < 4; ++s) {
    h8 a0 = *(const h8*)(xh_s + (wave * 32 + l15) * 136 + s * 32 + lq * 8);
    h8 a1 = *(const h8*)(xh_s + (wave * 32 + 16 + l15) * 136 + s * 32 + lq * 8);
#pragma unroll
    for (int tt = 0; tt < 16; ++tt) {
      h8 b = *(const h8*)(wg + ((s * 16 + tt) * 64 + lane) * 8);
      acc[0][tt] = __builtin_amdgcn_mfma_f32_16x16x32_f16(a0, b, acc[0][tt], 0, 0, 0);
      acc[1][tt] = __builtin_amdgcn_mfma_f32_16x16x32_f16(a1, b, acc[1][tt], 0, 0, 0);
    }
  }

#pragma unroll
  for (int g = 0; g < 2; ++g)
#pragma unroll
    for (int r = 0; r < 4; ++r) {
      int mg = n0 + wave * 32 + g * 16 + lq * 4 + r;
      bool vld = mg < NNODE;
      float o[4], ssum = 0.f, s2 = 0.f;
#pragma unroll
      for (int t0 = 0; t0 < 4; ++t0) {
        int f = t0 * 16 + l15;
        float rpre = acc[g][t0][r] + bsum[f];
        float zpre = acc[g][4 + t0][r] + bsum[64 + f];
        float ginv = acc[g][8 + t0][r] + bin_s[f];
        float ghnv = acc[g][12 + t0][r] + bhn_s[f];
        float rr = 1.f / (1.f + __expf(-rpre));
        float zz = 1.f / (1.f + __expf(-zpre));
        float hv = vld ? hid[(long)mg * 64 + f] : 0.f;
        float nn = tanhf(ginv + rr * ghnv);
        float oo = (1.f - zz) * nn + zz * hv;
        o[t0] = oo; ssum += oo; s2 += oo * oo;
      }
#pragma unroll
      for (int d = 1; d < 16; d <<= 1) {
        ssum += __shfl_xor(ssum, d);
        s2 += __shfl_xor(s2, d);
      }
      float mu = ssum * (1.f / 64.f);
      float var = s2 * (1.f / 64.f) - mu * mu;
      float rstd = rsqrtf(var + 1e-5f);
      if (vld)
#pragma unroll
        for (int t0 = 0; t0 < 4; ++t0) {
          int f = t0 * 16 + l15;
          out[(long)mg * 64 + f] = (o[t0] - mu) * rstd * gam_s[f] + bet_s[f];
        }
    }
}

extern "C" void kernel_launch(void* const* d_in, const int* in_sizes, int n_in,
                              void* d_out, int out_size, void* d_ws, size_t ws_size,
                              hipStream_t stream) {
  const float* node = (const float*)d_in[0];
  const float* edge = (const float*)d_in[1];
  const float* hid = (const float*)d_in[2];
  const int* src = (const int*)d_in[3];
  const int* dst = (const int*)d_in[4];
  const float* W1 = (const float*)d_in[5];
  const float* b1 = (const float*)d_in[6];
  const float* W2 = (const float*)d_in[7];
  const float* b2 = (const float*)d_in[8];
  const float* Wih = (const float*)d_in[9];
  const float* Whh = (const float*)d_in[10];
  const float* bih = (const float*)d_in[11];
  const float* bhh = (const float*)d_in[12];
  const float* gamma = (const float*)d_in[13];
  const float* beta = (const float*)d_in[14];

  char* ws = (char*)d_ws;
  f16* edgeh = (f16*)(ws + O_EDGEH);
  f16* w2g = (f16*)(ws + O_W2G);
  f16* b2g = (f16*)(ws + O_B2G);
  f16* w1g = (f16*)(ws + O_W1G);
  f16* wg = (f16*)(ws + O_WG);
  float* agg = (float*)(ws + O_AGG);

  k_prep<<<4542, 256, 0, stream>>>(edge, W1, W2, b2, Wih, Whh, edgeh, w1g, w2g, b2g, wg, agg);
  k_msg<<<782, 256, 0, stream>>>(node, src, dst, edgeh, w1g, w2g, b1, agg);
  k_node<<<94, 256, 0, stream>>>(agg, hid, wg, bih, bhh, gamma, beta, (float*)d_out);
}